// Round 9
// baseline (142.395 us; speedup 1.0000x reference)
//
#include <hip/hip_runtime.h>
#include <hip/hip_bf16.h>

// Flash-attention fwd, block-causal packed docs. fp32 HBM, bf16 MFMA.
// B=1, H=8, D=128. R18 = R17 (counted-vmcnt 3-buffer pipeline, key-split
// 8-wave compute, defer-rescale) + BALANCED CU PAIRING RESTORED:
//  - R16 bug found by audit: "heavy-first" qb=(15-(g>>2))+16*(g&3) gives
//    ntiles(g)=16-(g>>2), so CU pair (g,g+32) sums to 2*ntiles-8 ->
//    worst CU 24 tile-units, best 10. R11's pairing makes every pair sum
//    17. 41.6us/24 units = 1.73us/unit -> 17 units ~= 29.5us predicted.
//  - qb map (nqb==64): g<32 -> docs 0,1 descending (ntiles 16-(g&15));
//    g>=32 -> docs 2,3 ascending (ntiles (g&15)+1); pair (g,g+32) = 17
//    under CU(b)=(b%8,(b>>3)%32) refill model (validated R9/R11).
// Kept from R16/R17:
//  - 3 LDS buffers (96KB, 1 block/CU); per iter {s_waitcnt vmcnt(4);
//    s_barrier} then POST-barrier stage(t+2) -> loads span barriers,
//    vmcnt(0) only on last iter (T3/T4; R16: 47.5->42.4).
//  - T13 defer-rescale: oacc/l rescale only when __any(mx > m_r+8).
//  - 8-wave key-split: waves 0-3 keys [kt,kt+32), 4-7 [kt+32,kt+64);
//    swapped-operand QK^T (lane owns one query), P-in-registers PV,
//    LDS end-merge of the two key-half groups; setprio on MFMA.
//  - prepacked bf16 K / key-permuted V^T in d_ws (XOR-swizzled; gll16
//    linear dest + pre-swizzled src + swizzled read).
// Note: the 43us/268MB fillBufferAligned dispatches in top-5 are the
// harness re-poisoning d_ws each iteration - fixed cost, not ours.

#define HD 128
#define BR 64
#define BC 64

typedef __attribute__((ext_vector_type(8))) short short8;
typedef __attribute__((ext_vector_type(4))) float floatx4;

__device__ inline unsigned packbf2(float lo, float hi) {
    __hip_bfloat162 h2 = __float22bfloat162_rn(make_float2(lo, hi));
    return *reinterpret_cast<unsigned*>(&h2);   // low16 = lo, high16 = hi
}
__device__ inline short bfs(float f) {
    __hip_bfloat16 b = __float2bfloat16(f);
    return *reinterpret_cast<short*>(&b);
}

__device__ inline void gll16(const void* g, void* l) {
    __builtin_amdgcn_global_load_lds(
        (const __attribute__((address_space(1))) unsigned int*)g,
        (__attribute__((address_space(3))) unsigned int*)l, 16, 0, 0);
}

// ---------------- prepack: fp32 -> bf16, swizzled (V blocks first) --------
__global__ __launch_bounds__(256) void prepack(
    const float* __restrict__ K, const float* __restrict__ V,
    unsigned short* __restrict__ wsK, unsigned short* __restrict__ wsVT,
    int S)
{
    const int tid = threadIdx.x;
    const int nVblk = 8 * (S >> 6);
    const int bid = blockIdx.x;
    if (bid < nVblk) {
        // V^T via LDS: block = one (h, tile).
        __shared__ __align__(8) unsigned short sV[HD * 68];  // [d][r], stride 68 bf16
        const int ntile = S >> 6;
        const int h = bid / ntile;
        const int t = bid - h * ntile;
        const float* vb = V + ((size_t)h * S + t * 64) * HD;
        {
            const int rp = tid >> 3;
            const int dc = tid & 7;
            const int r0 = rp * 2;
            const int d0 = dc * 16;
            const float* p0 = vb + (size_t)r0 * HD + d0;
            const float* p1 = p0 + HD;
            float4 a0 = *(const float4*)(p0 + 0),  a1 = *(const float4*)(p0 + 4);
            float4 a2 = *(const float4*)(p0 + 8),  a3 = *(const float4*)(p0 + 12);
            float4 b0 = *(const float4*)(p1 + 0),  b1 = *(const float4*)(p1 + 4);
            float4 b2 = *(const float4*)(p1 + 8),  b3 = *(const float4*)(p1 + 12);
            float av[16] = {a0.x,a0.y,a0.z,a0.w, a1.x,a1.y,a1.z,a1.w,
                            a2.x,a2.y,a2.z,a2.w, a3.x,a3.y,a3.z,a3.w};
            float bv[16] = {b0.x,b0.y,b0.z,b0.w, b1.x,b1.y,b1.z,b1.w,
                            b2.x,b2.y,b2.z,b2.w, b3.x,b3.y,b3.z,b3.w};
            #pragma unroll
            for (int i = 0; i < 16; ++i) {
                unsigned pr = packbf2(av[i], bv[i]);   // keys r0 (lo), r0+1 (hi)
                *(unsigned*)((char*)sV + ((size_t)(d0 + i) * 68 + r0) * 2) = pr;
            }
        }
        __syncthreads();
        const int d  = tid >> 1;
        const int jj = tid & 1;
        char* dstrow = (char*)wsVT + (((size_t)(h * ntile + t) * HD + d) * 128);
        const int dx = (d & 7) << 4;
        const unsigned short* srow = sV + (size_t)d * 68;
        #pragma unroll
        for (int u = 0; u < 4; ++u) {
            const int j  = jj * 4 + u;
            const int k0 = (j >> 2) * 32 + (j & 3) * 4;
            uint2 lo = *(const uint2*)(srow + k0);        // keys k0..k0+3
            uint2 hi = *(const uint2*)(srow + k0 + 16);   // keys k0+16..k0+19
            uint4 w = make_uint4(lo.x, lo.y, hi.x, hi.y);
            *(uint4*)(dstrow + ((j * 16) ^ dx)) = w;
        }
    } else {
        // K: one 16B output chunk (8 bf16 <- 8 fp32) per thread, coalesced.
        const int cid = (bid - nVblk) * 256 + tid;
        const int row = cid >> 4;              // global row (h*S + r)
        const int c   = cid & 15;
        const float* src = K + (size_t)row * HD + c * 8;
        float4 f0 = *(const float4*)src;
        float4 f1 = *(const float4*)(src + 4);
        union { uint4 q; unsigned u[4]; } w;
        w.u[0] = packbf2(f0.x, f0.y); w.u[1] = packbf2(f0.z, f0.w);
        w.u[2] = packbf2(f1.x, f1.y); w.u[3] = packbf2(f1.z, f1.w);
        *(uint4*)((char*)wsK + (size_t)row * 256 + ((c * 16) ^ ((row & 7) << 4))) = w.q;
    }
}

// ---------------- main attention kernel ----------------
__global__ __launch_bounds__(512, 1) void fa_fwd(
    const float* __restrict__ Q,
    const unsigned short* __restrict__ wsK,
    const unsigned short* __restrict__ wsVT,
    const int* __restrict__ cu_seqlens, int n_cu,
    float* __restrict__ O,
    int S)
{
    __shared__ alignas(16) __hip_bfloat16 sK3[3][BC * HD];    // 3 x 16KB
    __shared__ alignas(16) unsigned int   sVT3[3][HD * 32];   // 3 x 16KB

    const int tid  = threadIdx.x;
    const int wave = tid >> 6;
    const int gp   = wave >> 2;             // key-half group 0/1
    const int wsub = wave & 3;              // query sub-block 0..3
    const int lane = tid & 63;
    const int quad = lane >> 4;
    const int l16  = lane & 15;
    const int kx   = (l16 & 7) << 4;        // read-side XOR (matches prepack)

    const int nqb = S / BR;
    const int h   = blockIdx.x & 7;
    const int g   = (int)(blockIdx.x >> 3);
    // balanced pairing: (g, g+32) ntiles sum to 17 (R11-proven)
    int qb;
    if (nqb == 64) {
        if (g < 32) qb = (g >> 4) * 16 + (15 - (g & 15));        // docs 0,1 desc
        else        qb = 32 + (((g - 32) >> 4) * 16) + (g & 15); // docs 2,3 asc
    } else {
        qb = nqb - 1 - g;
    }
    const int q0    = qb * BR;
    const int qw    = q0 + wsub * 16;
    const int qlane = qw + l16;     // the ONE query this lane owns

    // ---- block-uniform doc geometry ----
    int blk_ds = 0;
    for (int i = 0; i < n_cu; ++i) {
        int c = cu_seqlens[i];
        if (c <= q0) blk_ds = c;
    }
    const int k_begin = blk_ds & ~(BC - 1);
    const int ntiles  = (q0 + BR - 1 - k_begin) / BC + 1;

    // ---- staging: 4x global_load_lds dwordx4 per thread (8 waves) ----
    // waves 0-3 stage sK (4KB each), waves 4-7 stage sVT (4KB each).
    const char* gkb = (const char*)wsK + (size_t)h * S * 256;
    const char* gvb = (const char*)wsVT + (size_t)h * (S >> 6) * 16384;
    const int wofs = (wave & 3) * 4096;
    const int lo = wofs + lane * 16;
    auto stage = [&](int kt, int buf) {
        if (gp == 0) {
            const char* gk = gkb + (size_t)kt * 256 + lo;
            char* lk = (char*)&sK3[buf][0] + wofs;         // wave-uniform base
            #pragma unroll
            for (int c = 0; c < 4; ++c) gll16(gk + c * 1024, lk + c * 1024);
        } else {
            const char* gv = gvb + (size_t)(kt >> 6) * 16384 + lo;
            char* lv = (char*)&sVT3[buf][0] + wofs;
            #pragma unroll
            for (int c = 0; c < 4; ++c) gll16(gv + c * 1024, lv + c * 1024);
        }
    };

    const size_t hoff = (size_t)h * S * HD;
    const float* Qh = Q + hoff;
    float*       Oh = O + hoff;

    // ---- Q fragments FIRST (their vmcnt retires before the stages') ----
    short8 aq[4];
    {
        const float* qp = Qh + (size_t)qlane * HD + quad * 8;
        #pragma unroll
        for (int ks = 0; ks < 4; ++ks) {
            float4 a0 = *(const float4*)(qp + ks * 32);
            float4 a1 = *(const float4*)(qp + ks * 32 + 4);
            short8 a;
            a[0] = bfs(a0.x); a[1] = bfs(a0.y); a[2] = bfs(a0.z); a[3] = bfs(a0.w);
            a[4] = bfs(a1.x); a[5] = bfs(a1.y); a[6] = bfs(a1.z); a[7] = bfs(a1.w);
            aq[ks] = a;
        }
    }

    // ---- per-lane doc start ----
    int ds_lane = 0;
    for (int i = 0; i < n_cu; ++i) {
        int c = cu_seqlens[i];
        if (c <= qlane) ds_lane = c;
    }

    // ---- pipeline prologue: stage tiles 0,1 into bufs 0,1 ----
    stage(k_begin, 0);
    if (ntiles > 1) stage(k_begin + BC, 1);

    // oacc[dt][r] = O^T partial for THIS key-half: d=dt*16+quad*4+r, q=qlane
    floatx4 oacc[8];
    #pragma unroll
    for (int dt = 0; dt < 8; ++dt) oacc[dt] = (floatx4){0.f, 0.f, 0.f, 0.f};
    float m_r = -1e30f, l_r = 0.f;

    const float sl = 0.08838834764831845f * 1.4426950408889634f;

    int buf = 0;
    for (int it = 0; it < ntiles; ++it) {
        const int kt = k_begin + it * BC;

        // counted wait: own stage(it) retired (allow stage(it+1)'s 4 in
        // flight), then barrier -> all waves' stage(it) retired. vmcnt(0)
        // only on the last iteration.
        if (it + 1 < ntiles) {
            asm volatile("s_waitcnt vmcnt(4)\n\ts_barrier" ::: "memory");
        } else {
            asm volatile("s_waitcnt vmcnt(0)\n\ts_barrier" ::: "memory");
        }

        // issue stage(it+2) POST-barrier: its target buffer was last read at
        // iter it-1, which every wave finished before this barrier.
        if (it + 2 < ntiles) {
            int b2 = buf + 2; if (b2 >= 3) b2 -= 3;
            stage(kt + 2 * BC, b2);
        }

        if (kt + gp * 32 <= qw + 15) {       // wave-uniform key-half active
            const char* kbase = (const char*)&sK3[buf][0];
            const char* vbase = (const char*)&sVT3[buf][0];

            // ---- S^T = K Q^T over this wave's 32 keys (2 ct blocks) ----
            floatx4 sc[2];
            __builtin_amdgcn_s_setprio(1);
            #pragma unroll
            for (int ctl = 0; ctl < 2; ++ctl) {
                const int ct = 2 * gp + ctl;
                if (kt + ct * 16 <= qw + 15) {   // wave-uniform
                    floatx4 c = (floatx4){0.f, 0.f, 0.f, 0.f};
                    #pragma unroll
                    for (int ks = 0; ks < 4; ++ks) {
                        short8 a = *(const short8*)(kbase + (ct * 16 + l16) * 256
                                                    + (((ks * 4 + quad) << 4) ^ kx));
                        c = __builtin_amdgcn_mfma_f32_16x16x32_bf16(a, aq[ks], c, 0, 0, 0);
                    }
                    sc[ctl] = c;
                } else {
                    sc[ctl] = (floatx4){-1e30f, -1e30f, -1e30f, -1e30f};
                }
            }
            __builtin_amdgcn_s_setprio(0);

            // ---- mask + scale ----
            #pragma unroll
            for (int ctl = 0; ctl < 2; ++ctl) {
                if (kt + (2 * gp + ctl) * 16 <= qw + 15) {
                    #pragma unroll
                    for (int r = 0; r < 4; ++r) {
                        const int key = kt + (2 * gp + ctl) * 16 + quad * 4 + r;
                        const bool valid = (key <= qlane) && (key >= ds_lane);
                        float s = sc[ctl][r] * sl;
                        sc[ctl][r] = valid ? s : -1e30f;
                    }
                }
            }

            // ---- online softmax over 8 values + 2 shfl ----
            float mx = fmaxf(fmaxf(fmaxf(sc[0][0], sc[0][1]), fmaxf(sc[0][2], sc[0][3])),
                             fmaxf(fmaxf(sc[1][0], sc[1][1]), fmaxf(sc[1][2], sc[1][3])));
            mx = fmaxf(mx, __shfl_xor(mx, 16, 64));
            mx = fmaxf(mx, __shfl_xor(mx, 32, 64));

            // T13 defer-rescale: skip the oacc/l rescale (32 AGPR-resident
            // muls + serial stage before PV) unless some lane's tile-max
            // exceeds m_r + 8. p bounded by 2^8; fp32 accum headroom ample.
            if (__any(mx > m_r + 8.f)) {
                const float mnew = fmaxf(m_r, mx);
                const float al   = exp2f(m_r - mnew);
                m_r = mnew;
                l_r *= al;
                #pragma unroll
                for (int dt = 0; dt < 8; ++dt) {
                    #pragma unroll
                    for (int r = 0; r < 4; ++r)
                        oacc[dt][r] *= al;
                }
            }
            const float live = (m_r > -1e29f) ? 1.f : 0.f;  // key-half never valid

            float ssum = 0.f;
            #pragma unroll
            for (int ctl = 0; ctl < 2; ++ctl) {
                #pragma unroll
                for (int r = 0; r < 4; ++r) {
                    float p = exp2f(sc[ctl][r] - m_r) * live;
                    sc[ctl][r] = p;
                    ssum += p;
                }
            }
            l_r += ssum;

            // ---- O^T += V^T P^T (this wave's ks = gp only) ----
            union { unsigned u[4]; short8 s; } pu;   // B-frag = own p-values
            pu.u[0] = packbf2(sc[0][0], sc[0][1]);
            pu.u[1] = packbf2(sc[0][2], sc[0][3]);
            pu.u[2] = packbf2(sc[1][0], sc[1][1]);
            pu.u[3] = packbf2(sc[1][2], sc[1][3]);
            __builtin_amdgcn_s_setprio(1);
            #pragma unroll
            for (int dt = 0; dt < 8; ++dt) {
                union { uint4 q; short8 s; } cv;
                cv.q = *(const uint4*)(vbase + (dt * 16 + l16) * 128
                                       + (((gp * 4 + quad) << 4) ^ kx));
                oacc[dt] = __builtin_amdgcn_mfma_f32_16x16x32_bf16(cv.s, pu.s, oacc[dt], 0, 0, 0);
            }
            __builtin_amdgcn_s_setprio(0);
        }

        ++buf; if (buf >= 3) buf = 0;
    }

    // ---- reduce l over quads (within key-half) ----
    l_r += __shfl_xor(l_r, 16, 64);
    l_r += __shfl_xor(l_r, 32, 64);

    __syncthreads();    // all compute done before LDS reuse (full drain OK here)

    // ---- cross-group merge via LDS (pair = waves wsub, wsub+4) ----
    // exact regardless of whether m_r is the true max (reference-point
    // identity: w = exp2(m_r - M), l/oacc are relative to m_r).
    float* obuf = (float*)&sK3[0][0];    // 32KB: 4 pairs x 8KB O-partial
    float* lbuf = (float*)&sVT3[0][0];   // m/l: 4 pairs x 128 floats
    if (gp == 1) {
        float* ob = obuf + wsub * 2048;
        #pragma unroll
        for (int dt = 0; dt < 8; ++dt) {
            const int sw = (dt ^ (lane & 7)) << 2;
            float4 st;
            st.x = oacc[dt][0]; st.y = oacc[dt][1];
            st.z = oacc[dt][2]; st.w = oacc[dt][3];
            *(float4*)(ob + lane * 32 + sw) = st;
        }
        if (quad == 0) {
            lbuf[wsub * 128 + l16]      = m_r;
            lbuf[wsub * 128 + 64 + l16] = l_r;
        }
    }
    __syncthreads();
    if (gp == 0) {
        const float m2 = lbuf[wsub * 128 + l16];
        const float l2 = lbuf[wsub * 128 + 64 + l16];
        const float M  = fmaxf(m_r, m2);
        const float w1 = exp2f(m_r - M);
        const float w2 = exp2f(m2 - M);
        const float inv = 1.0f / (w1 * l_r + w2 * l2);
        const float* ob = obuf + wsub * 2048;
        float* op = Oh + (size_t)qlane * HD + quad * 4;
        #pragma unroll
        for (int dt = 0; dt < 8; ++dt) {
            const int sw = (dt ^ (lane & 7)) << 2;
            float4 o2 = *(const float4*)(ob + lane * 32 + sw);
            float4 st;
            st.x = (w1 * oacc[dt][0] + w2 * o2.x) * inv;
            st.y = (w1 * oacc[dt][1] + w2 * o2.y) * inv;
            st.z = (w1 * oacc[dt][2] + w2 * o2.z) * inv;
            st.w = (w1 * oacc[dt][3] + w2 * o2.w) * inv;
            *(float4*)(op + dt * 16) = st;
        }
    }
}

extern "C" void kernel_launch(void* const* d_in, const int* in_sizes, int n_in,
                              void* d_out, int out_size, void* d_ws, size_t ws_size,
                              hipStream_t stream) {
    const float* q = (const float*)d_in[0];
    const float* k = (const float*)d_in[1];
    const float* v = (const float*)d_in[2];
    const int* cu = (const int*)d_in[3];
    const int n_cu = in_sizes[3];
    const int H = 8;
    const int S = in_sizes[0] / (H * HD);   // B=1
    float* out = (float*)d_out;

    const int nqb = S / BR;
    unsigned short* wsK  = (unsigned short*)d_ws;                 // H*S*256 B
    unsigned short* wsVT = wsK + (size_t)H * S * HD;              // H*S*256 B

    const int nVblk = H * (S >> 6);          // 512 (long blocks first)
    const int nKblk = (H * S) / 16;          // 2048
    prepack<<<dim3(nVblk + nKblk), dim3(256), 0, stream>>>(k, v, wsK, wsVT, S);

    dim3 grid(H * nqb);        // 512 blocks, 1 per CU resident (96KB LDS)
    dim3 block(512);           // 8 waves
    fa_fwd<<<grid, block, 0, stream>>>(q, wsK, wsVT, cu, n_cu, out, S);
}

// Round 10
// 126.491 us; speedup vs baseline: 1.1257x; 1.1257x over previous
//
#include <hip/hip_runtime.h>
#include <hip/hip_bf16.h>

// Flash-attention fwd, block-causal packed docs. fp32 HBM, bf16 MFMA.
// B=1, H=8, D=128. R19 = R17 config (LPT dispatch order, counted-wait
// pipeline, key-split waves, defer-rescale) with BC DOUBLED to 128:
//  - R18 falsified the STATIC block->CU pairing model (balanced pairs
//    regressed 42->55us). CP refills CUs dynamically in dispatch order =>
//    R16/R17's ntiles-DESCENDING dispatch order was accidental LPT
//    (makespan ~= avg 17 units). Schedule for dispatch-order LPT.
//  - Residual cost is ~1.6us/step of distributed per-step overhead
//    (8-wave barrier rendezvous, softmax serial chain, bubbles) that
//    micro-fixes didn't shrink (R16 -11%, R17 -2%) => AMORTIZE it:
//    BC=128 halves the steps (4352 -> 2304, makespan 17 -> 9/CU).
//  - waves 0-3 keys [kt,kt+64), waves 4-7 [kt+64,kt+128); per wave/step:
//    16 QK MFMA + 16 PV MFMA + 16-value softmax.
//  - LDS 2 x (32KB K + 32KB V) = 128KB, 1 block/CU. Depth-1 prefetch:
//    stage(t+1) issued POST-barrier(t) into buf(t-1) (all waves provably
//    done reading); step-top vmcnt(0) covers only loads issued a full
//    step (~2us) earlier -> free, not an R11-style drain.
//  - prepack unchanged (two adjacent 64-key V^T tiles are contiguous).
// Keeps: swapped-operand QK^T, P-in-registers PV, XOR-swizzled K/V^T
// (gll16 linear dest + pre-swizzled src + swizzled read), T13
// defer-rescale, setprio on MFMA, LDS end-merge of key-half groups.

#define HD 128
#define BR 64
#define BC 128

typedef __attribute__((ext_vector_type(8))) short short8;
typedef __attribute__((ext_vector_type(4))) float floatx4;

__device__ inline unsigned packbf2(float lo, float hi) {
    __hip_bfloat162 h2 = __float22bfloat162_rn(make_float2(lo, hi));
    return *reinterpret_cast<unsigned*>(&h2);   // low16 = lo, high16 = hi
}
__device__ inline short bfs(float f) {
    __hip_bfloat16 b = __float2bfloat16(f);
    return *reinterpret_cast<short*>(&b);
}

__device__ inline void gll16(const void* g, void* l) {
    __builtin_amdgcn_global_load_lds(
        (const __attribute__((address_space(1))) unsigned int*)g,
        (__attribute__((address_space(3))) unsigned int*)l, 16, 0, 0);
}

// ---------------- prepack: fp32 -> bf16, swizzled (V blocks first) --------
__global__ __launch_bounds__(256) void prepack(
    const float* __restrict__ K, const float* __restrict__ V,
    unsigned short* __restrict__ wsK, unsigned short* __restrict__ wsVT,
    int S)
{
    const int tid = threadIdx.x;
    const int nVblk = 8 * (S >> 6);
    const int bid = blockIdx.x;
    if (bid < nVblk) {
        // V^T via LDS: block = one (h, 64-key tile).
        __shared__ __align__(8) unsigned short sV[HD * 68];  // [d][r], stride 68 bf16
        const int ntile = S >> 6;
        const int h = bid / ntile;
        const int t = bid - h * ntile;
        const float* vb = V + ((size_t)h * S + t * 64) * HD;
        {
            const int rp = tid >> 3;
            const int dc = tid & 7;
            const int r0 = rp * 2;
            const int d0 = dc * 16;
            const float* p0 = vb + (size_t)r0 * HD + d0;
            const float* p1 = p0 + HD;
            float4 a0 = *(const float4*)(p0 + 0),  a1 = *(const float4*)(p0 + 4);
            float4 a2 = *(const float4*)(p0 + 8),  a3 = *(const float4*)(p0 + 12);
            float4 b0 = *(const float4*)(p1 + 0),  b1 = *(const float4*)(p1 + 4);
            float4 b2 = *(const float4*)(p1 + 8),  b3 = *(const float4*)(p1 + 12);
            float av[16] = {a0.x,a0.y,a0.z,a0.w, a1.x,a1.y,a1.z,a1.w,
                            a2.x,a2.y,a2.z,a2.w, a3.x,a3.y,a3.z,a3.w};
            float bv[16] = {b0.x,b0.y,b0.z,b0.w, b1.x,b1.y,b1.z,b1.w,
                            b2.x,b2.y,b2.z,b2.w, b3.x,b3.y,b3.z,b3.w};
            #pragma unroll
            for (int i = 0; i < 16; ++i) {
                unsigned pr = packbf2(av[i], bv[i]);   // keys r0 (lo), r0+1 (hi)
                *(unsigned*)((char*)sV + ((size_t)(d0 + i) * 68 + r0) * 2) = pr;
            }
        }
        __syncthreads();
        const int d  = tid >> 1;
        const int jj = tid & 1;
        char* dstrow = (char*)wsVT + (((size_t)(h * ntile + t) * HD + d) * 128);
        const int dx = (d & 7) << 4;
        const unsigned short* srow = sV + (size_t)d * 68;
        #pragma unroll
        for (int u = 0; u < 4; ++u) {
            const int j  = jj * 4 + u;
            const int k0 = (j >> 2) * 32 + (j & 3) * 4;
            uint2 lo = *(const uint2*)(srow + k0);        // keys k0..k0+3
            uint2 hi = *(const uint2*)(srow + k0 + 16);   // keys k0+16..k0+19
            uint4 w = make_uint4(lo.x, lo.y, hi.x, hi.y);
            *(uint4*)(dstrow + ((j * 16) ^ dx)) = w;
        }
    } else {
        // K: one 16B output chunk (8 bf16 <- 8 fp32) per thread, coalesced.
        const int cid = (bid - nVblk) * 256 + tid;
        const int row = cid >> 4;              // global row (h*S + r)
        const int c   = cid & 15;
        const float* src = K + (size_t)row * HD + c * 8;
        float4 f0 = *(const float4*)src;
        float4 f1 = *(const float4*)(src + 4);
        union { uint4 q; unsigned u[4]; } w;
        w.u[0] = packbf2(f0.x, f0.y); w.u[1] = packbf2(f0.z, f0.w);
        w.u[2] = packbf2(f1.x, f1.y); w.u[3] = packbf2(f1.z, f1.w);
        *(uint4*)((char*)wsK + (size_t)row * 256 + ((c * 16) ^ ((row & 7) << 4))) = w.q;
    }
}

// ---------------- main attention kernel ----------------
__global__ __launch_bounds__(512, 1) void fa_fwd(
    const float* __restrict__ Q,
    const unsigned short* __restrict__ wsK,
    const unsigned short* __restrict__ wsVT,
    const int* __restrict__ cu_seqlens, int n_cu,
    float* __restrict__ O,
    int S)
{
    __shared__ alignas(16) __hip_bfloat16 sK2[2][BC * HD];    // 2 x 32KB
    __shared__ alignas(16) unsigned int   sVT2[2][2 * HD * 32]; // 2 x 32KB

    const int tid  = threadIdx.x;
    const int wave = tid >> 6;
    const int gp   = wave >> 2;             // key-half group 0/1 (64 keys each)
    const int wsub = wave & 3;              // query sub-block 0..3
    const int lane = tid & 63;
    const int quad = lane >> 4;
    const int l16  = lane & 15;
    const int kx   = (l16 & 7) << 4;        // read-side XOR (matches prepack)

    const int nqb = S / BR;
    const int h   = blockIdx.x & 7;
    const int g   = (int)(blockIdx.x >> 3);
    // LPT dispatch order: nt128 non-increasing across dispatch (R18 lesson:
    // CP refills CUs dynamically in dispatch order; heavy chains first).
    int qb;
    if (nqb == 64) {
        qb = (g & 3) * 16 + (15 - (g >> 2));   // doc interleave, idx desc
    } else {
        qb = nqb - 1 - g;
    }
    const int q0    = qb * BR;
    const int qw    = q0 + wsub * 16;
    const int qlane = qw + l16;     // the ONE query this lane owns

    // ---- block-uniform doc geometry (BC=128 aligned) ----
    int blk_ds = 0;
    for (int i = 0; i < n_cu; ++i) {
        int c = cu_seqlens[i];
        if (c <= q0) blk_ds = c;
    }
    const int k_begin = blk_ds & ~(BC - 1);
    const int ntiles  = (q0 + BR - 1 - k_begin) / BC + 1;

    // ---- staging: 8x global_load_lds dwordx4 per thread ----
    // waves 0-3 stage the 32KB K tile (8KB each); waves 4-7 the 32KB V pair.
    const char* gkb = (const char*)wsK + (size_t)h * S * 256;
    const char* gvb = (const char*)wsVT + (size_t)h * (S >> 6) * 16384;
    const int wofs = (wave & 3) * 8192;
    const int lo = wofs + lane * 16;
    auto stage = [&](int kt, int buf) {
        if (gp == 0) {
            const char* gk = gkb + (size_t)kt * 256 + lo;
            char* lk = (char*)&sK2[buf][0] + wofs;         // wave-uniform base
            #pragma unroll
            for (int c = 0; c < 8; ++c) gll16(gk + c * 1024, lk + c * 1024);
        } else {
            const char* gv = gvb + (size_t)(kt >> 6) * 16384 + lo;
            char* lv = (char*)&sVT2[buf][0] + wofs;
            #pragma unroll
            for (int c = 0; c < 8; ++c) gll16(gv + c * 1024, lv + c * 1024);
        }
    };

    const size_t hoff = (size_t)h * S * HD;
    const float* Qh = Q + hoff;
    float*       Oh = O + hoff;

    // ---- Q fragments FIRST (their vmcnt retires before the stages') ----
    short8 aq[4];
    {
        const float* qp = Qh + (size_t)qlane * HD + quad * 8;
        #pragma unroll
        for (int ks = 0; ks < 4; ++ks) {
            float4 a0 = *(const float4*)(qp + ks * 32);
            float4 a1 = *(const float4*)(qp + ks * 32 + 4);
            short8 a;
            a[0] = bfs(a0.x); a[1] = bfs(a0.y); a[2] = bfs(a0.z); a[3] = bfs(a0.w);
            a[4] = bfs(a1.x); a[5] = bfs(a1.y); a[6] = bfs(a1.z); a[7] = bfs(a1.w);
            aq[ks] = a;
        }
    }

    // ---- per-lane doc start ----
    int ds_lane = 0;
    for (int i = 0; i < n_cu; ++i) {
        int c = cu_seqlens[i];
        if (c <= qlane) ds_lane = c;
    }

    // ---- pipeline prologue: stage tile 0 into buf 0 ----
    stage(k_begin, 0);

    // oacc[dt][r] = O^T partial for THIS key-half: d=dt*16+quad*4+r, q=qlane
    floatx4 oacc[8];
    #pragma unroll
    for (int dt = 0; dt < 8; ++dt) oacc[dt] = (floatx4){0.f, 0.f, 0.f, 0.f};
    float m_r = -1e30f, l_r = 0.f;

    const float sl = 0.08838834764831845f * 1.4426950408889634f;

    for (int it = 0; it < ntiles; ++it) {
        const int kt  = k_begin + it * BC;
        const int buf = it & 1;

        // stage(it) was issued a full step earlier (prologue for it=0):
        // vmcnt(0) here is a free drain, then barrier -> all waves ready.
        asm volatile("s_waitcnt vmcnt(0)\n\ts_barrier" ::: "memory");

        // issue stage(it+1) POST-barrier into buf^1: every wave finished
        // reading buf^1 (= buf of it-1) before this barrier.
        if (it + 1 < ntiles) stage(kt + BC, buf ^ 1);

        if (kt + gp * 64 <= qw + 15) {       // wave-uniform key-half active
            const char* kbase = (const char*)&sK2[buf][0];
            const char* vbase = (const char*)&sVT2[buf][0] + gp * 16384;

            // ---- S^T = K Q^T over this wave's 64 keys (4 ct blocks) ----
            floatx4 sc[4];
            __builtin_amdgcn_s_setprio(1);
            #pragma unroll
            for (int ctl = 0; ctl < 4; ++ctl) {
                if (kt + gp * 64 + ctl * 16 <= qw + 15) {   // wave-uniform
                    floatx4 c = (floatx4){0.f, 0.f, 0.f, 0.f};
                    #pragma unroll
                    for (int ks = 0; ks < 4; ++ks) {
                        short8 a = *(const short8*)(kbase
                            + (gp * 64 + ctl * 16 + l16) * 256
                            + (((ks * 4 + quad) << 4) ^ kx));
                        c = __builtin_amdgcn_mfma_f32_16x16x32_bf16(a, aq[ks], c, 0, 0, 0);
                    }
                    sc[ctl] = c;
                } else {
                    sc[ctl] = (floatx4){-1e30f, -1e30f, -1e30f, -1e30f};
                }
            }
            __builtin_amdgcn_s_setprio(0);

            // ---- mask + scale ----
            #pragma unroll
            for (int ctl = 0; ctl < 4; ++ctl) {
                if (kt + gp * 64 + ctl * 16 <= qw + 15) {
                    #pragma unroll
                    for (int r = 0; r < 4; ++r) {
                        const int key = kt + gp * 64 + ctl * 16 + quad * 4 + r;
                        const bool valid = (key <= qlane) && (key >= ds_lane);
                        float s = sc[ctl][r] * sl;
                        sc[ctl][r] = valid ? s : -1e30f;
                    }
                }
            }

            // ---- online softmax over 16 values + 2 shfl ----
            float mx01 = fmaxf(fmaxf(fmaxf(sc[0][0], sc[0][1]), fmaxf(sc[0][2], sc[0][3])),
                               fmaxf(fmaxf(sc[1][0], sc[1][1]), fmaxf(sc[1][2], sc[1][3])));
            float mx23 = fmaxf(fmaxf(fmaxf(sc[2][0], sc[2][1]), fmaxf(sc[2][2], sc[2][3])),
                               fmaxf(fmaxf(sc[3][0], sc[3][1]), fmaxf(sc[3][2], sc[3][3])));
            float mx = fmaxf(mx01, mx23);
            mx = fmaxf(mx, __shfl_xor(mx, 16, 64));
            mx = fmaxf(mx, __shfl_xor(mx, 32, 64));

            // T13 defer-rescale: skip oacc/l rescale unless max moved > 8.
            if (__any(mx > m_r + 8.f)) {
                const float mnew = fmaxf(m_r, mx);
                const float al   = exp2f(m_r - mnew);
                m_r = mnew;
                l_r *= al;
                #pragma unroll
                for (int dt = 0; dt < 8; ++dt) {
                    #pragma unroll
                    for (int r = 0; r < 4; ++r)
                        oacc[dt][r] *= al;
                }
            }
            const float live = (m_r > -1e29f) ? 1.f : 0.f;  // key-half never valid

            float ssum = 0.f;
            #pragma unroll
            for (int ctl = 0; ctl < 4; ++ctl) {
                #pragma unroll
                for (int r = 0; r < 4; ++r) {
                    float p = exp2f(sc[ctl][r] - m_r) * live;
                    sc[ctl][r] = p;
                    ssum += p;
                }
            }
            l_r += ssum;

            // ---- O^T += V^T P^T over this wave's 64-key V tile ----
            __builtin_amdgcn_s_setprio(1);
            #pragma unroll
            for (int ks = 0; ks < 2; ++ks) {
                if (kt + gp * 64 + ks * 32 <= qw + 15) {    // wave-uniform
                    union { unsigned u[4]; short8 s; } pu;  // B-frag = own p's
                    pu.u[0] = packbf2(sc[2*ks][0],   sc[2*ks][1]);
                    pu.u[1] = packbf2(sc[2*ks][2],   sc[2*ks][3]);
                    pu.u[2] = packbf2(sc[2*ks+1][0], sc[2*ks+1][1]);
                    pu.u[3] = packbf2(sc[2*ks+1][2], sc[2*ks+1][3]);
                    #pragma unroll
                    for (int dt = 0; dt < 8; ++dt) {
                        union { uint4 q; short8 s; } cv;
                        cv.q = *(const uint4*)(vbase + (dt * 16 + l16) * 128
                                               + (((ks * 4 + quad) << 4) ^ kx));
                        oacc[dt] = __builtin_amdgcn_mfma_f32_16x16x32_bf16(cv.s, pu.s, oacc[dt], 0, 0, 0);
                    }
                }
            }
            __builtin_amdgcn_s_setprio(0);
        }
    }

    // ---- reduce l over quads (within key-half) ----
    l_r += __shfl_xor(l_r, 16, 64);
    l_r += __shfl_xor(l_r, 32, 64);

    __syncthreads();    // all compute done before LDS reuse (full drain OK here)

    // ---- cross-group merge via LDS (pair = waves wsub, wsub+4) ----
    // exact regardless of whether m_r is the true max (reference-point
    // identity: w = exp2(m_r - M); l/oacc are relative to m_r).
    float* obuf = (float*)&sK2[0][0];    // 32KB: 4 pairs x 8KB O-partial
    float* lbuf = (float*)&sVT2[0][0];   // m/l: 4 pairs x 128 floats
    if (gp == 1) {
        float* ob = obuf + wsub * 2048;
        #pragma unroll
        for (int dt = 0; dt < 8; ++dt) {
            const int sw = (dt ^ (lane & 7)) << 2;
            float4 st;
            st.x = oacc[dt][0]; st.y = oacc[dt][1];
            st.z = oacc[dt][2]; st.w = oacc[dt][3];
            *(float4*)(ob + lane * 32 + sw) = st;
        }
        if (quad == 0) {
            lbuf[wsub * 128 + l16]      = m_r;
            lbuf[wsub * 128 + 64 + l16] = l_r;
        }
    }
    __syncthreads();
    if (gp == 0) {
        const float m2 = lbuf[wsub * 128 + l16];
        const float l2 = lbuf[wsub * 128 + 64 + l16];
        const float M  = fmaxf(m_r, m2);
        const float w1 = exp2f(m_r - M);
        const float w2 = exp2f(m2 - M);
        const float inv = 1.0f / (w1 * l_r + w2 * l2);
        const float* ob = obuf + wsub * 2048;
        float* op = Oh + (size_t)qlane * HD + quad * 4;
        #pragma unroll
        for (int dt = 0; dt < 8; ++dt) {
            const int sw = (dt ^ (lane & 7)) << 2;
            float4 o2 = *(const float4*)(ob + lane * 32 + sw);
            float4 st;
            st.x = (w1 * oacc[dt][0] + w2 * o2.x) * inv;
            st.y = (w1 * oacc[dt][1] + w2 * o2.y) * inv;
            st.z = (w1 * oacc[dt][2] + w2 * o2.z) * inv;
            st.w = (w1 * oacc[dt][3] + w2 * o2.w) * inv;
            *(float4*)(op + dt * 16) = st;
        }
    }
}

extern "C" void kernel_launch(void* const* d_in, const int* in_sizes, int n_in,
                              void* d_out, int out_size, void* d_ws, size_t ws_size,
                              hipStream_t stream) {
    const float* q = (const float*)d_in[0];
    const float* k = (const float*)d_in[1];
    const float* v = (const float*)d_in[2];
    const int* cu = (const int*)d_in[3];
    const int n_cu = in_sizes[3];
    const int H = 8;
    const int S = in_sizes[0] / (H * HD);   // B=1
    float* out = (float*)d_out;

    const int nqb = S / BR;
    unsigned short* wsK  = (unsigned short*)d_ws;                 // H*S*256 B
    unsigned short* wsVT = wsK + (size_t)H * S * HD;              // H*S*256 B

    const int nVblk = H * (S >> 6);          // 512 (long blocks first)
    const int nKblk = (H * S) / 16;          // 2048
    prepack<<<dim3(nVblk + nKblk), dim3(256), 0, stream>>>(k, v, wsK, wsVT, S);

    dim3 grid(H * nqb);        // 512 blocks, 1 per CU resident (128KB LDS)
    dim3 block(512);           // 8 waves
    fa_fwd<<<grid, block, 0, stream>>>(q, wsK, wsVT, cu, n_cu, out, S);
}